// Round 1
// baseline (622.640 us; speedup 1.0000x reference)
//
#include <hip/hip_runtime.h>
#include <math.h>

#define BB 4
#define SS 4096
#define DD 4096
#define EE 64
#define ROWS (BB * SS)
#define EPSF 1e-10f

// ---------------------------------------------------------------------------
// Kernel 1: router GEMM [ROWS,D] x [D,E] -> logits, fused softmax-load accum.
// grid 512, block 256 (4 waves). Block = 32 rows; wave = 8 rows; lane = expert.
// ---------------------------------------------------------------------------
__global__ __launch_bounds__(256) void k_gemm_load(
    const float* __restrict__ h, const float* __restrict__ wr,
    float* __restrict__ logits, float* __restrict__ g_load) {
  __shared__ float h_s[32][64];   // 8 KiB  (row, k)
  __shared__ float w_s[64][64];   // 16 KiB (k, e)
  __shared__ float load_s[64];

  const int t = threadIdx.x;
  const int lane = t & 63;
  const int wv = t >> 6;
  const int row0 = blockIdx.x * 32;
  const int wrow = wv * 8;

  float acc[8] = {0.f, 0.f, 0.f, 0.f, 0.f, 0.f, 0.f, 0.f};

  for (int k0 = 0; k0 < DD; k0 += 64) {
    // stage h tile: 32 rows x 64 k (2 float4 per thread, coalesced)
#pragma unroll
    for (int i = 0; i < 2; ++i) {
      int f = t + 256 * i;
      int r = f >> 4, kq = (f & 15) * 4;
      *(float4*)&h_s[r][kq] =
          *(const float4*)&h[(size_t)(row0 + r) * DD + k0 + kq];
    }
    // stage w tile: 64 k x 64 e (4 float4 per thread, fully contiguous)
#pragma unroll
    for (int i = 0; i < 4; ++i) {
      int f = t + 256 * i;
      int k = f >> 4, eq = (f & 15) * 4;
      *(float4*)&w_s[k][eq] = *(const float4*)&wr[(size_t)(k0 + k) * EE + eq];
    }
    __syncthreads();

#pragma unroll
    for (int k = 0; k < 64; k += 4) {
      float w0 = w_s[k + 0][lane];
      float w1 = w_s[k + 1][lane];
      float w2 = w_s[k + 2][lane];
      float w3 = w_s[k + 3][lane];
#pragma unroll
      for (int r = 0; r < 8; ++r) {
        float4 hv = *(const float4*)&h_s[wrow + r][k];  // wave-uniform bcast
        acc[r] = fmaf(hv.x, w0, acc[r]);
        acc[r] = fmaf(hv.y, w1, acc[r]);
        acc[r] = fmaf(hv.z, w2, acc[r]);
        acc[r] = fmaf(hv.w, w3, acc[r]);
      }
    }
    __syncthreads();
  }

  // epilogue: write raw logits, wave softmax per row, accumulate expert load
  float lsum = 0.f;
#pragma unroll
  for (int r = 0; r < 8; ++r) {
    int row = row0 + wrow + r;
    logits[(size_t)row * EE + lane] = acc[r];
    float m = acc[r];
#pragma unroll
    for (int off = 32; off > 0; off >>= 1)
      m = fmaxf(m, __shfl_xor(m, off, 64));
    float p = __expf(acc[r] - m);
    float s = p;
#pragma unroll
    for (int off = 32; off > 0; off >>= 1) s += __shfl_xor(s, off, 64);
    lsum += p / s;
  }

  if (t < 64) load_s[t] = 0.f;
  __syncthreads();
  atomicAdd(&load_s[lane], lsum);
  __syncthreads();
  if (t < 64) atomicAdd(&g_load[t], load_s[t]);
}

// ---------------------------------------------------------------------------
// Kernel 2: penalty -> log(load/mean + eps). 1 block x 64 threads.
// ---------------------------------------------------------------------------
__global__ void k_penalty(const float* __restrict__ g_load,
                          float* __restrict__ g_lp) {
  int t = threadIdx.x;
  float v = g_load[t];
  float s = v;
#pragma unroll
  for (int off = 32; off > 0; off >>= 1) s += __shfl_xor(s, off, 64);
  float mean = s * (1.f / 64.f);
  float pen = v / (mean + EPSF);
  g_lp[t] = logf(pen + EPSF);
}

// ---------------------------------------------------------------------------
// Kernel 3: adjusted logits (in place) + top-2 indices (written as floats).
// grid ROWS/4, block 256 (wave = row, lane = expert).
// ---------------------------------------------------------------------------
__global__ __launch_bounds__(256) void k_top2(float* __restrict__ logits,
                                              const float* __restrict__ g_lp,
                                              float* __restrict__ idx_out) {
  int t = threadIdx.x;
  int lane = t & 63;
  int wv = t >> 6;
  int row = blockIdx.x * 4 + wv;
  size_t base = (size_t)row * EE;

  float a = logits[base + lane] - g_lp[lane];
  logits[base + lane] = a;

  // argmax with jax tie-break (smallest index wins among equal values)
  float v = a;
  int idx = lane;
#pragma unroll
  for (int off = 32; off > 0; off >>= 1) {
    float ov = __shfl_xor(v, off, 64);
    int oi = __shfl_xor(idx, off, 64);
    if (ov > v || (ov == v && oi < idx)) { v = ov; idx = oi; }
  }
  int i1 = idx;

  float a2 = (lane == i1) ? -INFINITY : a;
  v = a2;
  idx = lane;
#pragma unroll
  for (int off = 32; off > 0; off >>= 1) {
    float ov = __shfl_xor(v, off, 64);
    int oi = __shfl_xor(idx, off, 64);
    if (ov > v || (ov == v && oi < idx)) { v = ov; idx = oi; }
  }
  int i2 = idx;

  if (lane == 0) {
    idx_out[(size_t)row * 2 + 0] = (float)i1;
    idx_out[(size_t)row * 2 + 1] = (float)i2;
  }
}

// ---------------------------------------------------------------------------
extern "C" void kernel_launch(void* const* d_in, const int* in_sizes, int n_in,
                              void* d_out, int out_size, void* d_ws,
                              size_t ws_size, hipStream_t stream) {
  const float* h = (const float*)d_in[0];   // [4,4096,4096]
  const float* wr = (const float*)d_in[1];  // [4096,64]
  float* out = (float*)d_out;
  float* logits = out;                          // ROWS*EE floats
  float* idx_out = out + (size_t)ROWS * EE;     // ROWS*2 values (as float)
  float* g_load = (float*)d_ws;                 // 64 floats
  float* g_lp = g_load + 64;                    // 64 floats

  hipMemsetAsync(d_ws, 0, 64 * sizeof(float), stream);
  k_gemm_load<<<512, 256, 0, stream>>>(h, wr, logits, g_load);
  k_penalty<<<1, 64, 0, stream>>>(g_load, g_lp);
  k_top2<<<ROWS / 4, 256, 0, stream>>>(logits, g_lp, idx_out);
}